// Round 10
// baseline (28.335 us; speedup 1.0000x reference)
//
#include <hip/hip_runtime.h>

#define PNUM    1024
#define NB      128
#define NBLOCKS (NB * 16)

typedef _Float16 h2 __attribute__((ext_vector_type(2)));
typedef _Float16 h4 __attribute__((ext_vector_type(4)));

// gt LDS: pad +1 word every 8 -> in-loop b32 reads, banks (9s+4j+c)%32 = 2/bank (free)
#define PW(e) ((e) + ((e) >> 3))
// pred LDS: stride-34 rows of 32 elements -> b64 reads, bank-pairs 17j%16 distinct.

// smooth-L1 identity: sl1(d) = m*(|d| - 0.5m), m = min(|d|,1)   (5 packed ops)
#define SL1(acc, p, g) do {                               \
    h2 d_ = (p) - (g);                                    \
    h2 a_ = __builtin_elementwise_abs(d_);                \
    h2 m_ = __builtin_elementwise_min(a_, one2);          \
    h2 t_ = __builtin_elementwise_fma(m_, nh2, a_);       \
    (acc) = __builtin_elementwise_fma(m_, t_, (acc)); } while (0)

// One group: pred elements e0..e0+3 (two ds_read_b64) vs window n0..n10 = gt
// elements kbase+e0 .. +10; loads n7..n10 fresh (b32, odd starts).
#define GROUP(e0, n0,n1,n2,n3,n4,n5,n6,n7,n8,n9,n10) do {            \
    h4 pa = *(const h4*)(Pp + (e0));                                 \
    h4 pb = *(const h4*)(Pp + (e0) + 2);                             \
    h2 p0 = pa.lo, p1 = pa.hi, p2 = pb.lo, p3 = pb.hi;               \
    n7  = Gp[PW((e0)+7)];  n8  = Gp[PW((e0)+8)];                     \
    n9  = Gp[PW((e0)+9)];  n10 = Gp[PW((e0)+10)];                    \
    SL1(a0,p0,n0); SL1(a1,p0,n1); SL1(a2,p0,n2); SL1(a3,p0,n3);      \
    SL1(a4,p0,n4); SL1(a5,p0,n5); SL1(a6,p0,n6); SL1(a7,p0,n7);      \
    SL1(a0,p1,n1); SL1(a1,p1,n2); SL1(a2,p1,n3); SL1(a3,p1,n4);      \
    SL1(a4,p1,n5); SL1(a5,p1,n6); SL1(a6,p1,n7); SL1(a7,p1,n8);      \
    SL1(a0,p2,n2); SL1(a1,p2,n3); SL1(a2,p2,n4); SL1(a3,p2,n5);      \
    SL1(a4,p2,n6); SL1(a5,p2,n7); SL1(a6,p2,n8); SL1(a7,p2,n9);      \
    SL1(a0,p3,n3); SL1(a1,p3,n4); SL1(a2,p3,n5); SL1(a3,p3,n6);      \
    SL1(a4,p3,n7); SL1(a5,p3,n8); SL1(a6,p3,n9); SL1(a7,p3,n10);     \
  } while (0)

// One block = (batch b, 64 consecutive shifts). 256 threads =
// 8 shift-slots (8 shifts each, rolling 11-wide gt window) x 32 j-slots (32 j each).
// NO atomics (R8: fused agent-scope atomic tail collapses codegen to 20 VGPR).
// (256,8): force VGPR<=64 so all 8 blocks/CU are resident (grid = exactly 8/CU).
__global__ __launch_bounds__(256, 8) void poly_cost_kernel(
    const float* __restrict__ pred, const float* __restrict__ gt,
    float* __restrict__ block_min) {
  __shared__ h2    pred_s[1088];     // 32 rows x 34 words
  __shared__ h2    gt_s[1223];       // PW(1087)=1222
  __shared__ float partial[4][64];

  const int b     = blockIdx.x >> 4;
  const int chunk = blockIdx.x & 15;
  const int t     = threadIdx.x;

  const float4* pred4 = (const float4*)(pred + (size_t)b * (PNUM * 2));
  const float4* gt4   = (const float4*)(gt   + (size_t)b * (PNUM * 2));
  const int gb2 = chunk * 32;        // gt float4 base

  #pragma unroll
  for (int r = 0; r < 2; ++r) {
    int p = t + r * 256;             // float4 index = h2 elements 2p, 2p+1
    float4 v = pred4[p];
    int w = 34 * (p >> 4) + ((2 * p) & 31);
    pred_s[w]     = h2{(_Float16)v.x, (_Float16)v.y};
    pred_s[w + 1] = h2{(_Float16)v.z, (_Float16)v.w};
  }
  #pragma unroll
  for (int r = 0; r < 2; ++r) {
    int u = t + r * 256;
    float4 v = gt4[(gb2 + u) & 511];
    int w = PW(2 * u);               // 2u even -> pair never crosses pad boundary
    gt_s[w]     = h2{(_Float16)v.x, (_Float16)v.y};
    gt_s[w + 1] = h2{(_Float16)v.z, (_Float16)v.w};
  }
  if (t < 32) {
    int u = t + 512;
    float4 v = gt4[(gb2 + u) & 511];
    int w = PW(2 * u);
    gt_s[w]     = h2{(_Float16)v.x, (_Float16)v.y};
    gt_s[w + 1] = h2{(_Float16)v.z, (_Float16)v.w};
  }
  __syncthreads();

  const int sslot = t & 7;           // shifts i = chunk*64 + sslot*8 + s, s=0..7
  const int jslot = t >> 3;          // j = jslot*32 + jj, jj=0..31
  const h2* Pp = pred_s + 34 * jslot;             // stride-34 pred row
  const h2* Gp = gt_s   + 9 * sslot + 36 * jslot; // PW(8*sslot+32*jslot)

  const h2 one2 = {(_Float16)1.0f,  (_Float16)1.0f};
  const h2 nh2  = {(_Float16)-0.5f, (_Float16)-0.5f};
  h2 a0 = {(_Float16)0.0f, (_Float16)0.0f};
  h2 a1 = a0, a2 = a0, a3 = a0, a4 = a0, a5 = a0, a6 = a0, a7 = a0;

  // window vars w0..w10; preload gt elements 0..6 (PW(0..6)=0..6)
  h2 w0 = Gp[0], w1 = Gp[1], w2 = Gp[2], w3 = Gp[3];
  h2 w4 = Gp[4], w5 = Gp[5], w6 = Gp[6];
  h2 w7, w8, w9, w10;

  // rotation by 4 mod 11: start indices 0,4,8,1,5,9,2,6
  GROUP( 0, w0,w1,w2,w3,w4,w5,w6,w7,w8,w9,w10);
  GROUP( 4, w4,w5,w6,w7,w8,w9,w10,w0,w1,w2,w3);
  GROUP( 8, w8,w9,w10,w0,w1,w2,w3,w4,w5,w6,w7);
  GROUP(12, w1,w2,w3,w4,w5,w6,w7,w8,w9,w10,w0);
  GROUP(16, w5,w6,w7,w8,w9,w10,w0,w1,w2,w3,w4);
  GROUP(20, w9,w10,w0,w1,w2,w3,w4,w5,w6,w7,w8);
  GROUP(24, w2,w3,w4,w5,w6,w7,w8,w9,w10,w0,w1);
  GROUP(28, w6,w7,w8,w9,w10,w0,w1,w2,w3,w4,w5);

  // ---- reduce over jslot (lane bits 3..5) via shuffles, named floats only
  float f0 = (float)a0.x + (float)a0.y, f1 = (float)a1.x + (float)a1.y;
  float f2 = (float)a2.x + (float)a2.y, f3 = (float)a3.x + (float)a3.y;
  float f4 = (float)a4.x + (float)a4.y, f5 = (float)a5.x + (float)a5.y;
  float f6 = (float)a6.x + (float)a6.y, f7 = (float)a7.x + (float)a7.y;
#define JRED(f) f += __shfl_xor(f, 8); f += __shfl_xor(f, 16); f += __shfl_xor(f, 32)
  JRED(f0); JRED(f1); JRED(f2); JRED(f3); JRED(f4); JRED(f5); JRED(f6); JRED(f7);
#undef JRED

  const int wid = t >> 6, lane = t & 63;
  if ((lane & 56) == 0) {            // lanes 0..7: sslot = lane
    float* pp = &partial[wid][lane * 8];
    pp[0] = f0; pp[1] = f1; pp[2] = f2; pp[3] = f3;
    pp[4] = f4; pp[5] = f5; pp[6] = f6; pp[7] = f7;
  }
  __syncthreads();

  // ---- per-block: sum 4 wave-partials per shift, min over 64 shifts
  if (t < 64) {
    float sum = partial[0][t] + partial[1][t] + partial[2][t] + partial[3][t];
    float dis = sum * (1.0f / 1024.0f);
    #pragma unroll
    for (int off = 32; off; off >>= 1)
      dis = fminf(dis, __shfl_xor(dis, off));
    if (t == 0) block_min[blockIdx.x] = dis;   // plain store, no atomics
  }
}

// Kernel 2: per-batch min over 16 block-mins, then mean over 128 batches.
__global__ __launch_bounds__(128) void poly_reduce_kernel(
    const float* __restrict__ block_min, float* __restrict__ out) {
  const int b = threadIdx.x;
  float m = block_min[b * 16];
  #pragma unroll
  for (int c = 1; c < 16; ++c) m = fminf(m, block_min[b * 16 + c]);
  #pragma unroll
  for (int off = 32; off; off >>= 1) m += __shfl_xor(m, off);
  __shared__ float wsum[2];
  if ((b & 63) == 0) wsum[b >> 6] = m;
  __syncthreads();
  if (b == 0) out[0] = (wsum[0] + wsum[1]) * (1.0f / NB);
}

extern "C" void kernel_launch(void* const* d_in, const int* in_sizes, int n_in,
                              void* d_out, int out_size, void* d_ws, size_t ws_size,
                              hipStream_t stream) {
  const float* pred = (const float*)d_in[0];
  const float* gt   = (const float*)d_in[1];
  float* out        = (float*)d_out;
  float* block_min  = (float*)d_ws;   // 2048 floats

  poly_cost_kernel<<<NBLOCKS, 256, 0, stream>>>(pred, gt, block_min);
  poly_reduce_kernel<<<1, 128, 0, stream>>>(block_min, out);
}